// Round 4
// baseline (255.451 us; speedup 1.0000x reference)
//
#include <hip/hip_runtime.h>
#include <cstdint>

// Problem constants (fixed by the reference)
#define BATCH  64
#define NATOMS 1024
#define DEG    5
#define FIN    256
#define OOUT   256
#define NBF    6
#define KDIM   262          // FIN + NBF
#define KP     288          // padded K (9 x 32)
#define NKT    9            // k-tiles of 32
#define MROWS  (BATCH * NATOMS)   // 65536
#define MT     64           // atom rows per block (fused kernel)
#define AS     296          // Afeat LDS row stride in shorts (37*8: 16B-aligned, 2-way banks)

typedef __attribute__((ext_vector_type(8))) short bf16x8;   // MFMA A/B frag (4 VGPR)
typedef __attribute__((ext_vector_type(4))) float f32x4;    // MFMA C/D frag

__device__ __forceinline__ unsigned short f2bf(float x) {
    unsigned u = __float_as_uint(x);
    u += 0x7fff + ((u >> 16) & 1);          // round-to-nearest-even
    return (unsigned short)(u >> 16);
}
__device__ __forceinline__ float bf2f(unsigned short h) {
    return __uint_as_float(((unsigned)h) << 16);
}
__device__ __forceinline__ float sigmoidf_(float x) {
    return 1.f / (1.f + __expf(-x));
}

// ---------------------------------------------------------------------------
// Kernel 1: pre-swizzle degW[5] into MFMA B-fragment lane order (bf16).
// Wsw[g][t][lane][8]: col = g*16+(lane&15), k = t*32+(lane>>4)*8+j, zero k>=262.
// 16 groups x 9 ktiles x 64 lanes x 8 = 147,456 B; L2-resident for the GEMM.
// ---------------------------------------------------------------------------
__global__ __launch_bounds__(256)
void convert_w_kernel(const float* __restrict__ degW, unsigned short* __restrict__ Wsw)
{
    const int idx = blockIdx.x * 256 + threadIdx.x;      // over 16*9*64 = 9216 frag-lanes
    if (idx >= 16 * NKT * 64) return;
    const int lane = idx & 63;
    const int t    = (idx >> 6) % NKT;
    const int g    = (idx >> 6) / NKT;
    const int col  = g * 16 + (lane & 15);
    const int k0   = t * 32 + (lane >> 4) * 8;
    const float* __restrict__ W5 = degW + (size_t)DEG * KDIM * OOUT;
    unsigned short* dst = Wsw + (size_t)idx * 8;
    #pragma unroll
    for (int j = 0; j < 8; ++j) {
        const int k = k0 + j;
        dst[j] = f2bf((k < KDIM) ? W5[(size_t)k * OOUT + col] : 0.f);
    }
}

// ---------------------------------------------------------------------------
// Kernel 2: fused gather + bf16 MFMA GEMM + odd-degree fixup.
// Block = 64 atom rows x 256 outs; 4 waves, each wave all 64 rows x 64 cols.
// XCD swizzle: all 16 blocks of a batch target one XCD (atoms slice L2-hot).
// ---------------------------------------------------------------------------
__global__ __launch_bounds__(256, 4)
void nfp_fused_kernel(const float* __restrict__ atoms, const float* __restrict__ bonds,
                      const int* __restrict__ edges, const unsigned short* __restrict__ Wsw,
                      const float* __restrict__ degW, const float* __restrict__ bias,
                      float* __restrict__ out)
{
    __shared__ short Afeat[MT * AS];     // 37,888 B
    __shared__ int   edg[MT * DEG];      // 320 entries — MUST be loop-staged (320 > 256)
    __shared__ int   deg_lds[MT];

    const int tid  = threadIdx.x;
    const int lane = tid & 63;
    const int wave = tid >> 6;

    // XCD-aware mapping: blocks 16 per batch; batch b -> XCD b%8 (heuristic).
    const int bid   = blockIdx.x;                 // 1024 blocks
    const int xcd   = bid & 7;
    const int per   = bid >> 3;                   // 0..127 within XCD
    const int batch = (per >> 4) * 8 + xcd;       // 8 batches per XCD
    const int blk   = per & 15;
    const int row0  = batch * NATOMS + blk * MT;

    // ---- stage edges (strided: MT*DEG = 320 > blockDim 256!) ----
    for (int i = tid; i < MT * DEG; i += 256)
        edg[i] = edges[row0 * DEG + i];
    __syncthreads();
    if (tid < MT) {
        int dc = 0;
        #pragma unroll
        for (int d = 0; d < DEG; ++d) dc += (edg[tid * DEG + d] != -1) ? 1 : 0;
        deg_lds[tid] = dc;
    }

    // ---- gather: wave w handles rows [w*16, w*16+16) ----
    for (int mi = 0; mi < 16; ++mi) {
        const int m = wave * 16 + mi;
        float4 v = *(const float4*)&atoms[((size_t)row0 + m) * FIN + lane * 4];
        #pragma unroll
        for (int d = 0; d < DEG; ++d) {
            const int e = edg[m * DEG + d];                 // wave-uniform
            if (e >= 0) {
                const float4 nv = *(const float4*)&atoms[((size_t)(batch << 10) + e) * FIN + lane * 4];
                v.x += nv.x; v.y += nv.y; v.z += nv.z; v.w += nv.w;
            }
        }
        ushort4 us;
        us.x = f2bf(v.x); us.y = f2bf(v.y); us.z = f2bf(v.z); us.w = f2bf(v.w);
        *(ushort4*)&Afeat[m * AS + lane * 4] = us;
        if (lane < 32) {                                    // k = 256..287 (zeros past 261)
            float bv = 0.f;
            if (lane < NBF) {
                const float* bb = bonds + ((size_t)row0 + m) * (DEG * NBF);
                #pragma unroll
                for (int d = 0; d < DEG; ++d) bv += bb[d * NBF + lane];
            }
            Afeat[m * AS + FIN + lane] = f2bf(bv);
        }
    }
    __syncthreads();

    // ---- MFMA main loop: wave computes 64 rows x cols [wave*64, wave*64+64) ----
    const int fr = lane & 15;
    const int q  = lane >> 4;
    const int wn = wave * 64;

    f32x4 acc[4][4];
    #pragma unroll
    for (int i = 0; i < 4; ++i)
        #pragma unroll
        for (int j = 0; j < 4; ++j)
            acc[i][j] = (f32x4){0.f, 0.f, 0.f, 0.f};

    #pragma unroll
    for (int t = 0; t < NKT; ++t) {
        bf16x8 af[4], bfr[4];
        #pragma unroll
        for (int i = 0; i < 4; ++i)
            af[i] = *(const bf16x8*)&Afeat[(i * 16 + fr) * AS + t * 32 + q * 8]; // ds_read_b128
        #pragma unroll
        for (int j = 0; j < 4; ++j)      // coalesced 16B/lane, L2-resident 147 KB
            bfr[j] = *(const bf16x8*)&Wsw[((size_t)((wave * 4 + j) * NKT + t) * 64 + lane) * 8];
        #pragma unroll
        for (int i = 0; i < 4; ++i)
            #pragma unroll
            for (int j = 0; j < 4; ++j)
                acc[i][j] = __builtin_amdgcn_mfma_f32_16x16x32_bf16(af[i], bfr[j], acc[i][j], 0, 0, 0);
    }

    // ---- epilogue: C/D map col=lane&15, row=(lane>>4)*4+reg; skip odd rows ----
    #pragma unroll
    for (int j = 0; j < 4; ++j) {
        const int gn = wn + j * 16 + fr;
        const float bj = bias[gn];
        #pragma unroll
        for (int i = 0; i < 4; ++i) {
            #pragma unroll
            for (int r = 0; r < 4; ++r) {
                const int lm = i * 16 + q * 4 + r;          // local row
                if (deg_lds[lm] == DEG)
                    out[((size_t)row0 + lm) * OOUT + gn] = sigmoidf_(acc[i][j][r] + bj);
            }
        }
    }

    // ---- in-block fixup for rare deg != 5 rows (~0.3 per block) ----
    for (int m = 0; m < MT; ++m) {
        const int d = deg_lds[m];
        if (d == DEG) continue;                             // block-uniform branch
        const float* __restrict__ W = degW + (size_t)d * KDIM * OOUT;
        float a2 = 0.f;
        #pragma unroll 2
        for (int k = 0; k < KDIM; ++k)
            a2 += bf2f(Afeat[m * AS + k]) * W[(size_t)k * OOUT + tid];
        out[((size_t)row0 + m) * OOUT + tid] = sigmoidf_(a2 + bias[tid]);
    }
}

// ---------------------------------------------------------------------------
// Fallback (R1 fp32 kernel, no workspace) if ws_size is too small.
// ---------------------------------------------------------------------------
#define FMT  32
#define FKT  32
#define FKPAD 288
__global__ __launch_bounds__(256, 2)
void nfp_conv_fallback(const float* __restrict__ atoms, const float* __restrict__ bonds,
                       const int* __restrict__ edges, const float* __restrict__ degW,
                       const float* __restrict__ bias, float* __restrict__ out)
{
    __shared__ float feats[FMT * FKPAD];
    __shared__ float wtile[FKT * OOUT];
    __shared__ int   edg[FMT * DEG];
    __shared__ int   deg_lds[FMT];
    __shared__ int   odd_list[FMT];
    __shared__ int   odd_cnt;
    __shared__ float b_lds[OOUT];

    const int tid = threadIdx.x, bid = blockIdx.x;
    const int batch = bid >> 5, a0 = (bid & 31) * FMT;
    const size_t atom_base = (size_t)batch * NATOMS;

    b_lds[tid] = bias[tid];
    if (tid == 0) odd_cnt = 0;
    if (tid < FMT * DEG) {
        const int m = tid / DEG, d = tid % DEG;
        edg[tid] = edges[(atom_base + a0 + m) * DEG + d];
    }
    __syncthreads();
    if (tid < FMT) {
        int dc = 0;
        #pragma unroll
        for (int d = 0; d < DEG; ++d) dc += (edg[tid * DEG + d] != -1) ? 1 : 0;
        deg_lds[tid] = dc;
        if (dc != DEG) { const int idx = atomicAdd(&odd_cnt, 1); odd_list[idx] = tid; }
    }
    __syncthreads();
    {
        const int f = tid;
        for (int m = 0; m < FMT; ++m) {
            float v = atoms[(atom_base + a0 + m) * FIN + f];
            #pragma unroll
            for (int d = 0; d < DEG; ++d) {
                const int e = edg[m * DEG + d];
                if (e >= 0) v += atoms[(atom_base + e) * FIN + f];
            }
            feats[m * FKPAD + f] = v;
        }
        #pragma unroll
        for (int t = 0; t < 4; ++t) {
            const int idx = t * 256 + tid;
            const int m = idx >> 5, kk = idx & 31;
            float v = 0.f;
            if (kk < NBF) {
                const size_t bb = (atom_base + a0 + m) * (size_t)(DEG * NBF);
                #pragma unroll
                for (int d = 0; d < DEG; ++d) v += bonds[bb + d * NBF + kk];
            }
            feats[m * FKPAD + FIN + kk] = v;
        }
    }
    const float* __restrict__ W5 = degW + (size_t)DEG * KDIM * OOUT;
    float acc[4][8];
    #pragma unroll
    for (int i = 0; i < 4; ++i)
        #pragma unroll
        for (int j = 0; j < 8; ++j) acc[i][j] = 0.f;
    const int tx = tid & 31, ty = tid >> 5;
    for (int kt = 0; kt < FKPAD; kt += FKT) {
        __syncthreads();
        #pragma unroll
        for (int t = 0; t < FKT; ++t) {
            const int k = kt + t;
            wtile[t * OOUT + tid] = (k < KDIM) ? W5[(size_t)k * OOUT + tid] : 0.f;
        }
        __syncthreads();
        #pragma unroll 4
        for (int r = 0; r < FKT; ++r) {
            float a_frag[4];
            #pragma unroll
            for (int i = 0; i < 4; ++i) a_frag[i] = feats[(ty * 4 + i) * FKPAD + kt + r];
            float w_frag[8];
            #pragma unroll
            for (int j = 0; j < 8; ++j) w_frag[j] = wtile[r * OOUT + tx + j * 32];
            #pragma unroll
            for (int i = 0; i < 4; ++i)
                #pragma unroll
                for (int j = 0; j < 8; ++j) acc[i][j] += a_frag[i] * w_frag[j];
        }
    }
    #pragma unroll
    for (int i = 0; i < 4; ++i) {
        const int m = ty * 4 + i;
        if (deg_lds[m] == DEG) {
            const size_t row = (atom_base + a0 + m) * (size_t)OOUT;
            #pragma unroll
            for (int j = 0; j < 8; ++j) {
                const int o = tx + j * 32;
                out[row + o] = sigmoidf_(acc[i][j] + b_lds[o]);
            }
        }
    }
    const int ocnt = odd_cnt;
    for (int i = 0; i < ocnt; ++i) {
        const int m = odd_list[i], d = deg_lds[m];
        const float* __restrict__ W = degW + (size_t)d * KDIM * OOUT;
        float a2 = 0.f;
        for (int k = 0; k < KDIM; ++k) a2 += feats[m * FKPAD + k] * W[(size_t)k * OOUT + tid];
        const size_t row = (atom_base + a0 + m) * (size_t)OOUT;
        out[row + tid] = sigmoidf_(a2 + b_lds[tid]);
    }
}

// ---------------------------------------------------------------------------
extern "C" void kernel_launch(void* const* d_in, const int* in_sizes, int n_in,
                              void* d_out, int out_size, void* d_ws, size_t ws_size,
                              hipStream_t stream) {
    const float* atoms = (const float*)d_in[0];
    const float* bonds = (const float*)d_in[1];
    const int*   edges = (const int*)d_in[2];
    const float* degW  = (const float*)d_in[3];
    const float* bias  = (const float*)d_in[4];
    float* out = (float*)d_out;

    const size_t WSW_BYTES = (size_t)16 * NKT * 64 * 8 * 2;   // 147,456

    if (ws_size < WSW_BYTES) {
        nfp_conv_fallback<<<BATCH * (NATOMS / FMT), 256, 0, stream>>>(
            atoms, bonds, edges, degW, bias, out);
        return;
    }

    unsigned short* Wsw = (unsigned short*)d_ws;
    convert_w_kernel<<<(16 * NKT * 64 + 255) / 256, 256, 0, stream>>>(degW, Wsw);
    nfp_fused_kernel<<<MROWS / MT, 256, 0, stream>>>(
        atoms, bonds, edges, Wsw, degW, bias, out);
}

// Round 5
// 228.248 us; speedup vs baseline: 1.1192x; 1.1192x over previous
//
#include <hip/hip_runtime.h>
#include <cstdint>

// Problem constants (fixed by the reference)
#define BATCH  64
#define NATOMS 1024
#define DEG    5
#define FIN    256
#define OOUT   256
#define NBF    6
#define KDIM   262          // FIN + NBF
#define KP     288          // padded K (9 x 32)
#define NKT    9            // k-tiles of 32
#define MROWS  (BATCH * NATOMS)   // 65536
#define MT     32           // atom rows per block (fused kernel)
#define AS     296          // Afeat LDS row stride in shorts (37*8: 16B-aligned, 2-way banks)

typedef __attribute__((ext_vector_type(8))) short bf16x8;   // MFMA A/B frag (4 VGPR)
typedef __attribute__((ext_vector_type(4))) float f32x4;    // MFMA C/D frag

__device__ __forceinline__ unsigned short f2bf(float x) {
    unsigned u = __float_as_uint(x);
    u += 0x7fff + ((u >> 16) & 1);          // round-to-nearest-even
    return (unsigned short)(u >> 16);
}
__device__ __forceinline__ float bf2f(unsigned short h) {
    return __uint_as_float(((unsigned)h) << 16);
}
__device__ __forceinline__ float sigmoidf_(float x) {
    return 1.f / (1.f + __expf(-x));
}

// ---------------------------------------------------------------------------
// Kernel 1: pre-swizzle degW[5] into MFMA B-fragment lane order (bf16).
// Wsw[g][t][lane][8]: col = g*16+(lane&15), k = t*32+(lane>>4)*8+j, zero k>=262.
// 16 groups x 9 ktiles x 64 lanes x 8 = 147,456 B; L2-resident for the GEMM.
// ---------------------------------------------------------------------------
__global__ __launch_bounds__(256)
void convert_w_kernel(const float* __restrict__ degW, unsigned short* __restrict__ Wsw)
{
    const int idx = blockIdx.x * 256 + threadIdx.x;      // over 16*9*64 = 9216 frag-lanes
    if (idx >= 16 * NKT * 64) return;
    const int lane = idx & 63;
    const int t    = (idx >> 6) % NKT;
    const int g    = (idx >> 6) / NKT;
    const int col  = g * 16 + (lane & 15);
    const int k0   = t * 32 + (lane >> 4) * 8;
    const float* __restrict__ W5 = degW + (size_t)DEG * KDIM * OOUT;
    unsigned short* dst = Wsw + (size_t)idx * 8;
    #pragma unroll
    for (int j = 0; j < 8; ++j) {
        const int k = k0 + j;
        dst[j] = f2bf((k < KDIM) ? W5[(size_t)k * OOUT + col] : 0.f);
    }
}

// ---------------------------------------------------------------------------
// Kernel 2: fused gather + bf16 MFMA GEMM + odd-degree fixup.
// Block = 32 atom rows x 256 outs; 4 waves; wave w computes 32 rows x 64 cols.
// Gather is branch-free (clamped index + flag-multiply) so all 5 neighbor
// loads stay in flight; MT=32 keeps acc at 32 AGPRs so ~96 arch VGPRs remain
// for load pipelining under __launch_bounds__(256,4).   [R4 post-mortem]
// ---------------------------------------------------------------------------
__global__ __launch_bounds__(256, 4)
void nfp_fused_kernel(const float* __restrict__ atoms, const float* __restrict__ bonds,
                      const int* __restrict__ edges, const unsigned short* __restrict__ Wsw,
                      const float* __restrict__ degW, const float* __restrict__ bias,
                      float* __restrict__ out)
{
    __shared__ short Afeat[MT * AS];     // 18,944 B
    __shared__ int   edg[MT * DEG];      // 160 entries
    __shared__ int   deg_lds[MT];

    const int tid  = threadIdx.x;
    const int lane = tid & 63;
    const int wave = tid >> 6;

    // XCD-aware mapping: 32 blocks per batch; batch b -> XCD b%8 (heuristic).
    // Resident per XCD: ~128 blocks = 4 batches = 4 MB atoms ~= L2 size.
    const int bid   = blockIdx.x;                 // 2048 blocks
    const int xcd   = bid & 7;
    const int per   = bid >> 3;                   // 0..255 within XCD
    const int batch = (per >> 5) * 8 + xcd;       // 8 batch-groups of 8
    const int blk   = per & 31;
    const int row0  = batch * NATOMS + blk * MT;

    // ---- stage edges (MT*DEG = 160 <= 256: single shot) ----
    if (tid < MT * DEG) edg[tid] = edges[row0 * DEG + tid];
    __syncthreads();
    if (tid < MT) {
        int dc = 0;
        #pragma unroll
        for (int d = 0; d < DEG; ++d) dc += (edg[tid * DEG + d] != -1) ? 1 : 0;
        deg_lds[tid] = dc;
    }

    // ---- gather: wave w handles rows [w*8, w*8+8), branch-free ----
    const float* __restrict__ abase = atoms + ((size_t)batch << 10) * FIN;
    #pragma unroll 2
    for (int mi = 0; mi < 8; ++mi) {
        const int m = wave * 8 + mi;
        int   ei[DEG];
        float fl[DEG];
        #pragma unroll
        for (int d = 0; d < DEG; ++d) {
            const int e = edg[m * DEG + d];
            ei[d] = (e >= 0) ? e : 0;             // clamped: always load row >= 0
            fl[d] = (e >= 0) ? 1.f : 0.f;
        }
        float4 v = *(const float4*)&atoms[((size_t)row0 + m) * FIN + lane * 4];
        float4 nv[DEG];
        #pragma unroll
        for (int d = 0; d < DEG; ++d)             // 5 independent loads, no branches
            nv[d] = *(const float4*)&abase[(size_t)ei[d] * FIN + lane * 4];
        #pragma unroll
        for (int d = 0; d < DEG; ++d) {
            v.x += fl[d] * nv[d].x; v.y += fl[d] * nv[d].y;
            v.z += fl[d] * nv[d].z; v.w += fl[d] * nv[d].w;
        }
        ushort4 us;
        us.x = f2bf(v.x); us.y = f2bf(v.y); us.z = f2bf(v.z); us.w = f2bf(v.w);
        *(ushort4*)&Afeat[m * AS + lane * 4] = us;
        if (lane < 32) {                          // k = 256..287 (zeros past 261)
            float bv = 0.f;
            if (lane < NBF) {
                const float* bb = bonds + ((size_t)row0 + m) * (DEG * NBF);
                #pragma unroll
                for (int d = 0; d < DEG; ++d) bv += bb[d * NBF + lane];
            }
            Afeat[m * AS + FIN + lane] = f2bf(bv);
        }
    }
    __syncthreads();

    // ---- MFMA: wave computes all 32 rows x cols [wave*64, wave*64+64) ----
    const int fr = lane & 15;
    const int q  = lane >> 4;
    const int wn = wave * 64;

    f32x4 acc[2][4];
    #pragma unroll
    for (int i = 0; i < 2; ++i)
        #pragma unroll
        for (int j = 0; j < 4; ++j)
            acc[i][j] = (f32x4){0.f, 0.f, 0.f, 0.f};

    #pragma unroll
    for (int t = 0; t < NKT; ++t) {
        bf16x8 af[2], bfr[4];
        #pragma unroll
        for (int i = 0; i < 2; ++i)
            af[i] = *(const bf16x8*)&Afeat[(i * 16 + fr) * AS + t * 32 + q * 8]; // ds_read_b128
        #pragma unroll
        for (int j = 0; j < 4; ++j)      // coalesced 16B/lane, L2-resident 147 KB
            bfr[j] = *(const bf16x8*)&Wsw[((size_t)((wave * 4 + j) * NKT + t) * 64 + lane) * 8];
        #pragma unroll
        for (int i = 0; i < 2; ++i)
            #pragma unroll
            for (int j = 0; j < 4; ++j)
                acc[i][j] = __builtin_amdgcn_mfma_f32_16x16x32_bf16(af[i], bfr[j], acc[i][j], 0, 0, 0);
    }

    // ---- epilogue: C/D map col=lane&15, row=(lane>>4)*4+reg; skip odd rows ----
    #pragma unroll
    for (int j = 0; j < 4; ++j) {
        const int gn = wn + j * 16 + fr;
        const float bj = bias[gn];
        #pragma unroll
        for (int i = 0; i < 2; ++i) {
            #pragma unroll
            for (int r = 0; r < 4; ++r) {
                const int lm = i * 16 + q * 4 + r;          // local row
                if (deg_lds[lm] == DEG)
                    out[((size_t)row0 + lm) * OOUT + gn] = sigmoidf_(acc[i][j][r] + bj);
            }
        }
    }

    // ---- in-block fixup for rare deg != 5 rows (~0.15 per block) ----
    for (int m = 0; m < MT; ++m) {
        const int d = deg_lds[m];
        if (d == DEG) continue;                             // block-uniform branch
        const float* __restrict__ W = degW + (size_t)d * KDIM * OOUT;
        float a2 = 0.f;
        #pragma unroll 2
        for (int k = 0; k < KDIM; ++k)
            a2 += bf2f(Afeat[m * AS + k]) * W[(size_t)k * OOUT + tid];
        out[((size_t)row0 + m) * OOUT + tid] = sigmoidf_(a2 + bias[tid]);
    }
}

// ---------------------------------------------------------------------------
// Fallback (R1 fp32 kernel, no workspace) if ws_size is too small.
// ---------------------------------------------------------------------------
#define FMT  32
#define FKT  32
#define FKPAD 288
__global__ __launch_bounds__(256, 2)
void nfp_conv_fallback(const float* __restrict__ atoms, const float* __restrict__ bonds,
                       const int* __restrict__ edges, const float* __restrict__ degW,
                       const float* __restrict__ bias, float* __restrict__ out)
{
    __shared__ float feats[FMT * FKPAD];
    __shared__ float wtile[FKT * OOUT];
    __shared__ int   edg[FMT * DEG];
    __shared__ int   deg_lds[FMT];
    __shared__ int   odd_list[FMT];
    __shared__ int   odd_cnt;
    __shared__ float b_lds[OOUT];

    const int tid = threadIdx.x, bid = blockIdx.x;
    const int batch = bid >> 5, a0 = (bid & 31) * FMT;
    const size_t atom_base = (size_t)batch * NATOMS;

    b_lds[tid] = bias[tid];
    if (tid == 0) odd_cnt = 0;
    if (tid < FMT * DEG) {
        const int m = tid / DEG, d = tid % DEG;
        edg[tid] = edges[(atom_base + a0 + m) * DEG + d];
    }
    __syncthreads();
    if (tid < FMT) {
        int dc = 0;
        #pragma unroll
        for (int d = 0; d < DEG; ++d) dc += (edg[tid * DEG + d] != -1) ? 1 : 0;
        deg_lds[tid] = dc;
        if (dc != DEG) { const int idx = atomicAdd(&odd_cnt, 1); odd_list[idx] = tid; }
    }
    __syncthreads();
    {
        const int f = tid;
        for (int m = 0; m < FMT; ++m) {
            float v = atoms[(atom_base + a0 + m) * FIN + f];
            #pragma unroll
            for (int d = 0; d < DEG; ++d) {
                const int e = edg[m * DEG + d];
                if (e >= 0) v += atoms[(atom_base + e) * FIN + f];
            }
            feats[m * FKPAD + f] = v;
        }
        #pragma unroll
        for (int t = 0; t < 4; ++t) {
            const int idx = t * 256 + tid;
            const int m = idx >> 5, kk = idx & 31;
            float v = 0.f;
            if (kk < NBF) {
                const size_t bb = (atom_base + a0 + m) * (size_t)(DEG * NBF);
                #pragma unroll
                for (int d = 0; d < DEG; ++d) v += bonds[bb + d * NBF + kk];
            }
            feats[m * FKPAD + FIN + kk] = v;
        }
    }
    const float* __restrict__ W5 = degW + (size_t)DEG * KDIM * OOUT;
    float acc[4][8];
    #pragma unroll
    for (int i = 0; i < 4; ++i)
        #pragma unroll
        for (int j = 0; j < 8; ++j) acc[i][j] = 0.f;
    const int tx = tid & 31, ty = tid >> 5;
    for (int kt = 0; kt < FKPAD; kt += FKT) {
        __syncthreads();
        #pragma unroll
        for (int t = 0; t < FKT; ++t) {
            const int k = kt + t;
            wtile[t * OOUT + tid] = (k < KDIM) ? W5[(size_t)k * OOUT + tid] : 0.f;
        }
        __syncthreads();
        #pragma unroll 4
        for (int r = 0; r < FKT; ++r) {
            float a_frag[4];
            #pragma unroll
            for (int i = 0; i < 4; ++i) a_frag[i] = feats[(ty * 4 + i) * FKPAD + kt + r];
            float w_frag[8];
            #pragma unroll
            for (int j = 0; j < 8; ++j) w_frag[j] = wtile[r * OOUT + tx + j * 32];
            #pragma unroll
            for (int i = 0; i < 4; ++i)
                #pragma unroll
                for (int j = 0; j < 8; ++j) acc[i][j] += a_frag[i] * w_frag[j];
        }
    }
    #pragma unroll
    for (int i = 0; i < 4; ++i) {
        const int m = ty * 4 + i;
        if (deg_lds[m] == DEG) {
            const size_t row = (atom_base + a0 + m) * (size_t)OOUT;
            #pragma unroll
            for (int j = 0; j < 8; ++j) {
                const int o = tx + j * 32;
                out[row + o] = sigmoidf_(acc[i][j] + b_lds[o]);
            }
        }
    }
    const int ocnt = odd_cnt;
    for (int i = 0; i < ocnt; ++i) {
        const int m = odd_list[i], d = deg_lds[m];
        const float* __restrict__ W = degW + (size_t)d * KDIM * OOUT;
        float a2 = 0.f;
        for (int k = 0; k < KDIM; ++k) a2 += feats[m * FKPAD + k] * W[(size_t)k * OOUT + tid];
        const size_t row = (atom_base + a0 + m) * (size_t)OOUT;
        out[row + tid] = sigmoidf_(a2 + b_lds[tid]);
    }
}

// ---------------------------------------------------------------------------
extern "C" void kernel_launch(void* const* d_in, const int* in_sizes, int n_in,
                              void* d_out, int out_size, void* d_ws, size_t ws_size,
                              hipStream_t stream) {
    const float* atoms = (const float*)d_in[0];
    const float* bonds = (const float*)d_in[1];
    const int*   edges = (const int*)d_in[2];
    const float* degW  = (const float*)d_in[3];
    const float* bias  = (const float*)d_in[4];
    float* out = (float*)d_out;

    const size_t WSW_BYTES = (size_t)16 * NKT * 64 * 8 * 2;   // 147,456

    if (ws_size < WSW_BYTES) {
        nfp_conv_fallback<<<BATCH * (NATOMS / FMT), 256, 0, stream>>>(
            atoms, bonds, edges, degW, bias, out);
        return;
    }

    unsigned short* Wsw = (unsigned short*)d_ws;
    convert_w_kernel<<<(16 * NKT * 64 + 255) / 256, 256, 0, stream>>>(degW, Wsw);
    nfp_fused_kernel<<<MROWS / MT, 256, 0, stream>>>(
        atoms, bonds, edges, Wsw, degW, bias, out);
}

// Round 6
// 198.270 us; speedup vs baseline: 1.2884x; 1.1512x over previous
//
#include <hip/hip_runtime.h>
#include <cstdint>

// Problem constants (fixed by the reference)
#define BATCH  64
#define NATOMS 1024
#define DEG    5
#define FIN    256
#define OOUT   256
#define NBF    6
#define KDIM   262          // FIN + NBF
#define KP     288          // padded K (9 x 32)
#define NKT    9            // k-tiles of 32
#define MROWS  (BATCH * NATOMS)   // 65536
#define MT     32           // atom rows per block (fused kernel)
#define AS     296          // Afeat LDS row stride in shorts (37*8: 16B-aligned, 2-way banks)

typedef __attribute__((ext_vector_type(8))) short bf16x8;   // MFMA A/B frag (4 VGPR)
typedef __attribute__((ext_vector_type(4))) float f32x4;    // MFMA C/D frag

__device__ __forceinline__ unsigned short f2bf(float x) {
    unsigned u = __float_as_uint(x);
    u += 0x7fff + ((u >> 16) & 1);          // round-to-nearest-even
    return (unsigned short)(u >> 16);
}
__device__ __forceinline__ float bf2f(unsigned short h) {
    return __uint_as_float(((unsigned)h) << 16);
}
__device__ __forceinline__ float sigmoidf_(float x) {
    return 1.f / (1.f + __expf(-x));
}

// ---------------------------------------------------------------------------
// Kernel 1: pre-swizzle degW[5] into MFMA B-fragment lane order (bf16).
// Wsw[g][t][lane][8]: col = g*16+(lane&15), k = t*32+(lane>>4)*8+j, zero k>=262.
// 16 groups x 9 ktiles x 64 lanes x 8 = 147,456 B; L2-resident for the GEMM.
// ---------------------------------------------------------------------------
__global__ __launch_bounds__(256)
void convert_w_kernel(const float* __restrict__ degW, unsigned short* __restrict__ Wsw)
{
    const int idx = blockIdx.x * 256 + threadIdx.x;      // over 16*9*64 = 9216 frag-lanes
    if (idx >= 16 * NKT * 64) return;
    const int lane = idx & 63;
    const int t    = (idx >> 6) % NKT;
    const int g    = (idx >> 6) / NKT;
    const int col  = g * 16 + (lane & 15);
    const int k0   = t * 32 + (lane >> 4) * 8;
    const float* __restrict__ W5 = degW + (size_t)DEG * KDIM * OOUT;
    unsigned short* dst = Wsw + (size_t)idx * 8;
    #pragma unroll
    for (int j = 0; j < 8; ++j) {
        const int k = k0 + j;
        dst[j] = f2bf((k < KDIM) ? W5[(size_t)k * OOUT + col] : 0.f);
    }
}

// ---------------------------------------------------------------------------
// Kernel 2: fused gather + bf16 MFMA GEMM + odd-degree fixup.
// R6: every latency site restructured for ILP —
//   gather: 2-row chunks, all 12 float4 loads issued before any accumulate
//   mfma:   B-frag register double-buffer (load t+1 during compute of t)
//   fixup:  4 independent accumulator chains so W loads pipeline
// ---------------------------------------------------------------------------
__global__ __launch_bounds__(256, 4)
void nfp_fused_kernel(const float* __restrict__ atoms, const float* __restrict__ bonds,
                      const int* __restrict__ edges, const unsigned short* __restrict__ Wsw,
                      const float* __restrict__ degW, const float* __restrict__ bias,
                      float* __restrict__ out)
{
    __shared__ short Afeat[MT * AS];     // 18,944 B
    __shared__ int   edg[MT * DEG];      // 160 entries
    __shared__ int   deg_lds[MT];

    const int tid  = threadIdx.x;
    const int lane = tid & 63;
    const int wave = tid >> 6;

    // XCD-aware mapping: 32 blocks per batch; batch b -> XCD b%8 (heuristic).
    const int bid   = blockIdx.x;                 // 2048 blocks
    const int xcd   = bid & 7;
    const int per   = bid >> 3;                   // 0..255 within XCD
    const int batch = (per >> 5) * 8 + xcd;       // 8 batch-groups of 8
    const int blk   = per & 31;
    const int row0  = batch * NATOMS + blk * MT;

    // ---- stage edges (MT*DEG = 160 <= 256: single shot) ----
    if (tid < MT * DEG) edg[tid] = edges[row0 * DEG + tid];
    __syncthreads();
    if (tid < MT) {
        int dc = 0;
        #pragma unroll
        for (int d = 0; d < DEG; ++d) dc += (edg[tid * DEG + d] != -1) ? 1 : 0;
        deg_lds[tid] = dc;
    }

    // ---- gather: wave w owns rows [w*8, w*8+8); 2-row two-phase chunks ----
    const float* __restrict__ abase = atoms + ((size_t)batch << 10) * FIN;
    const int selfrow = blk * MT;                 // row offset within batch
    #pragma unroll
    for (int c = 0; c < 4; ++c) {
        const int mb = wave * 8 + c * 2;
        float4 self[2];
        float4 nv[2][DEG];
        // phase 1: issue all 12 loads back-to-back (no dependent use between)
        #pragma unroll
        for (int r = 0; r < 2; ++r) {
            const int m = mb + r;
            self[r] = *(const float4*)&abase[(size_t)(selfrow + m) * FIN + lane * 4];
            #pragma unroll
            for (int d = 0; d < DEG; ++d) {
                const int e  = edg[m * DEG + d];
                const int ei = (e >= 0) ? e : 0;          // clamped (always legal)
                nv[r][d] = *(const float4*)&abase[(size_t)ei * FIN + lane * 4];
            }
        }
        // phase 2: accumulate (flags re-read from LDS, cheap) + convert + store
        #pragma unroll
        for (int r = 0; r < 2; ++r) {
            const int m = mb + r;
            float4 v = self[r];
            #pragma unroll
            for (int d = 0; d < DEG; ++d) {
                const float fl = (edg[m * DEG + d] >= 0) ? 1.f : 0.f;
                v.x += fl * nv[r][d].x; v.y += fl * nv[r][d].y;
                v.z += fl * nv[r][d].z; v.w += fl * nv[r][d].w;
            }
            ushort4 us;
            us.x = f2bf(v.x); us.y = f2bf(v.y); us.z = f2bf(v.z); us.w = f2bf(v.w);
            *(ushort4*)&Afeat[m * AS + lane * 4] = us;
        }
    }
    // ---- tail k = 256..287 (bond sums + zero pad), lane-parallel ----
    #pragma unroll
    for (int i = lane; i < 8 * 32; i += 64) {
        const int r  = i >> 5, kk = i & 31;
        const int m  = wave * 8 + r;
        float bv = 0.f;
        if (kk < NBF) {
            const float* bb = bonds + ((size_t)row0 + m) * (DEG * NBF) + kk;
            bv = bb[0] + bb[NBF] + bb[2 * NBF] + bb[3 * NBF] + bb[4 * NBF];
        }
        Afeat[m * AS + FIN + kk] = f2bf(bv);
    }
    __syncthreads();

    // ---- MFMA: wave computes all 32 rows x cols [wave*64, wave*64+64) ----
    const int fr = lane & 15;
    const int q  = lane >> 4;
    const int wn = wave * 64;

    f32x4 acc[2][4];
    #pragma unroll
    for (int i = 0; i < 2; ++i)
        #pragma unroll
        for (int j = 0; j < 4; ++j)
            acc[i][j] = (f32x4){0.f, 0.f, 0.f, 0.f};

    bf16x8 bcur[4], bnxt[4];
    #pragma unroll
    for (int j = 0; j < 4; ++j)
        bcur[j] = *(const bf16x8*)&Wsw[((size_t)((wave * 4 + j) * NKT) * 64 + lane) * 8];

    #pragma unroll
    for (int t = 0; t < NKT; ++t) {
        if (t + 1 < NKT) {                       // prefetch next k-tile's B frags
            #pragma unroll
            for (int j = 0; j < 4; ++j)
                bnxt[j] = *(const bf16x8*)&Wsw[((size_t)((wave * 4 + j) * NKT + t + 1) * 64 + lane) * 8];
        }
        bf16x8 af[2];
        #pragma unroll
        for (int i = 0; i < 2; ++i)
            af[i] = *(const bf16x8*)&Afeat[(i * 16 + fr) * AS + t * 32 + q * 8]; // ds_read_b128
        #pragma unroll
        for (int i = 0; i < 2; ++i)
            #pragma unroll
            for (int j = 0; j < 4; ++j)
                acc[i][j] = __builtin_amdgcn_mfma_f32_16x16x32_bf16(af[i], bcur[j], acc[i][j], 0, 0, 0);
        #pragma unroll
        for (int j = 0; j < 4; ++j) bcur[j] = bnxt[j];
    }

    // ---- epilogue: C/D map col=lane&15, row=(lane>>4)*4+reg; skip odd rows ----
    #pragma unroll
    for (int j = 0; j < 4; ++j) {
        const int gn = wn + j * 16 + fr;
        const float bj = bias[gn];
        #pragma unroll
        for (int i = 0; i < 2; ++i) {
            #pragma unroll
            for (int r = 0; r < 4; ++r) {
                const int lm = i * 16 + q * 4 + r;          // local row
                if (deg_lds[lm] == DEG)
                    __builtin_nontemporal_store(sigmoidf_(acc[i][j][r] + bj),
                                                &out[((size_t)row0 + lm) * OOUT + gn]);
            }
        }
    }

    // ---- in-block fixup for rare deg != 5 rows: 4 independent chains ----
    for (int m = 0; m < MT; ++m) {
        const int dg = deg_lds[m];
        if (dg == DEG) continue;                            // block-uniform branch
        const float* __restrict__ W = degW + (size_t)dg * KDIM * OOUT;
        float s0 = 0.f, s1 = 0.f, s2 = 0.f, s3 = 0.f;
        #pragma unroll 2
        for (int k = 0; k < 260; k += 4) {                  // loads pipeline: accs independent
            const float w0 = W[(size_t)(k + 0) * OOUT + tid];
            const float w1 = W[(size_t)(k + 1) * OOUT + tid];
            const float w2 = W[(size_t)(k + 2) * OOUT + tid];
            const float w3 = W[(size_t)(k + 3) * OOUT + tid];
            s0 += bf2f(Afeat[m * AS + k + 0]) * w0;
            s1 += bf2f(Afeat[m * AS + k + 1]) * w1;
            s2 += bf2f(Afeat[m * AS + k + 2]) * w2;
            s3 += bf2f(Afeat[m * AS + k + 3]) * w3;
        }
        s0 += bf2f(Afeat[m * AS + 260]) * W[(size_t)260 * OOUT + tid];
        s1 += bf2f(Afeat[m * AS + 261]) * W[(size_t)261 * OOUT + tid];
        const float x = ((s0 + s1) + (s2 + s3)) + bias[tid];
        out[((size_t)row0 + m) * OOUT + tid] = sigmoidf_(x);
    }
}

// ---------------------------------------------------------------------------
// Fallback (R1 fp32 kernel, no workspace) if ws_size is too small.
// ---------------------------------------------------------------------------
#define FMT  32
#define FKT  32
#define FKPAD 288
__global__ __launch_bounds__(256, 2)
void nfp_conv_fallback(const float* __restrict__ atoms, const float* __restrict__ bonds,
                       const int* __restrict__ edges, const float* __restrict__ degW,
                       const float* __restrict__ bias, float* __restrict__ out)
{
    __shared__ float feats[FMT * FKPAD];
    __shared__ float wtile[FKT * OOUT];
    __shared__ int   edg[FMT * DEG];
    __shared__ int   deg_lds[FMT];
    __shared__ int   odd_list[FMT];
    __shared__ int   odd_cnt;
    __shared__ float b_lds[OOUT];

    const int tid = threadIdx.x, bid = blockIdx.x;
    const int batch = bid >> 5, a0 = (bid & 31) * FMT;
    const size_t atom_base = (size_t)batch * NATOMS;

    b_lds[tid] = bias[tid];
    if (tid == 0) odd_cnt = 0;
    if (tid < FMT * DEG) {
        const int m = tid / DEG, d = tid % DEG;
        edg[tid] = edges[(atom_base + a0 + m) * DEG + d];
    }
    __syncthreads();
    if (tid < FMT) {
        int dc = 0;
        #pragma unroll
        for (int d = 0; d < DEG; ++d) dc += (edg[tid * DEG + d] != -1) ? 1 : 0;
        deg_lds[tid] = dc;
        if (dc != DEG) { const int idx = atomicAdd(&odd_cnt, 1); odd_list[idx] = tid; }
    }
    __syncthreads();
    {
        const int f = tid;
        for (int m = 0; m < FMT; ++m) {
            float v = atoms[(atom_base + a0 + m) * FIN + f];
            #pragma unroll
            for (int d = 0; d < DEG; ++d) {
                const int e = edg[m * DEG + d];
                if (e >= 0) v += atoms[(atom_base + e) * FIN + f];
            }
            feats[m * FKPAD + f] = v;
        }
        #pragma unroll
        for (int t = 0; t < 4; ++t) {
            const int idx = t * 256 + tid;
            const int m = idx >> 5, kk = idx & 31;
            float v = 0.f;
            if (kk < NBF) {
                const size_t bb = (atom_base + a0 + m) * (size_t)(DEG * NBF);
                #pragma unroll
                for (int d = 0; d < DEG; ++d) v += bonds[bb + d * NBF + kk];
            }
            feats[m * FKPAD + FIN + kk] = v;
        }
    }
    const float* __restrict__ W5 = degW + (size_t)DEG * KDIM * OOUT;
    float acc[4][8];
    #pragma unroll
    for (int i = 0; i < 4; ++i)
        #pragma unroll
        for (int j = 0; j < 8; ++j) acc[i][j] = 0.f;
    const int tx = tid & 31, ty = tid >> 5;
    for (int kt = 0; kt < FKPAD; kt += FKT) {
        __syncthreads();
        #pragma unroll
        for (int t = 0; t < FKT; ++t) {
            const int k = kt + t;
            wtile[t * OOUT + tid] = (k < KDIM) ? W5[(size_t)k * OOUT + tid] : 0.f;
        }
        __syncthreads();
        #pragma unroll 4
        for (int r = 0; r < FKT; ++r) {
            float a_frag[4];
            #pragma unroll
            for (int i = 0; i < 4; ++i) a_frag[i] = feats[(ty * 4 + i) * FKPAD + kt + r];
            float w_frag[8];
            #pragma unroll
            for (int j = 0; j < 8; ++j) w_frag[j] = wtile[r * OOUT + tx + j * 32];
            #pragma unroll
            for (int i = 0; i < 4; ++i)
                #pragma unroll
                for (int j = 0; j < 8; ++j) acc[i][j] += a_frag[i] * w_frag[j];
        }
    }
    #pragma unroll
    for (int i = 0; i < 4; ++i) {
        const int m = ty * 4 + i;
        if (deg_lds[m] == DEG) {
            const size_t row = (atom_base + a0 + m) * (size_t)OOUT;
            #pragma unroll
            for (int j = 0; j < 8; ++j) {
                const int o = tx + j * 32;
                out[row + o] = sigmoidf_(acc[i][j] + b_lds[o]);
            }
        }
    }
    const int ocnt = odd_cnt;
    for (int i = 0; i < ocnt; ++i) {
        const int m = odd_list[i], d = deg_lds[m];
        const float* __restrict__ W = degW + (size_t)d * KDIM * OOUT;
        float a2 = 0.f;
        for (int k = 0; k < KDIM; ++k) a2 += feats[m * FKPAD + k] * W[(size_t)k * OOUT + tid];
        const size_t row = (atom_base + a0 + m) * (size_t)OOUT;
        out[row + tid] = sigmoidf_(a2 + b_lds[tid]);
    }
}

// ---------------------------------------------------------------------------
extern "C" void kernel_launch(void* const* d_in, const int* in_sizes, int n_in,
                              void* d_out, int out_size, void* d_ws, size_t ws_size,
                              hipStream_t stream) {
    const float* atoms = (const float*)d_in[0];
    const float* bonds = (const float*)d_in[1];
    const int*   edges = (const int*)d_in[2];
    const float* degW  = (const float*)d_in[3];
    const float* bias  = (const float*)d_in[4];
    float* out = (float*)d_out;

    const size_t WSW_BYTES = (size_t)16 * NKT * 64 * 8 * 2;   // 147,456

    if (ws_size < WSW_BYTES) {
        nfp_conv_fallback<<<BATCH * (NATOMS / FMT), 256, 0, stream>>>(
            atoms, bonds, edges, degW, bias, out);
        return;
    }

    unsigned short* Wsw = (unsigned short*)d_ws;
    convert_w_kernel<<<(16 * NKT * 64 + 255) / 256, 256, 0, stream>>>(degW, Wsw);
    nfp_fused_kernel<<<MROWS / MT, 256, 0, stream>>>(
        atoms, bonds, edges, Wsw, degW, bias, out);
}